// Round 1
// baseline (222.691 us; speedup 1.0000x reference)
//
#include <hip/hip_runtime.h>

#define B_  32
#define C_  256
#define H_  56
#define W_  56
#define HW  3136      // H_*W_
#define KK  9
#define OC  2304      // C_*K*K
#define NPLANES (B_*C_)   // 8192

// ---------------------------------------------------------------------------
// Kernel 1: global average pool.  One block per (b,c) plane.
// pooled[plane] = mean(x[plane, :, :])
// ---------------------------------------------------------------------------
__global__ __launch_bounds__(256) void pool_kernel(const float* __restrict__ x,
                                                   float* __restrict__ pooled) {
    const int plane = blockIdx.x;                       // b*C + c
    const float4* xp = (const float4*)(x + (size_t)plane * HW);
    const int t = threadIdx.x;

    float s = 0.f;
    for (int i = t; i < HW / 4; i += 256) {             // 784 float4 strips
        float4 v = xp[i];
        s += v.x + v.y + v.z + v.w;
    }
    // wave (64-lane) shuffle reduction
    #pragma unroll
    for (int off = 32; off > 0; off >>= 1)
        s += __shfl_down(s, off, 64);

    __shared__ float wsum[4];
    const int lane = t & 63, wid = t >> 6;
    if (lane == 0) wsum[wid] = s;
    __syncthreads();
    if (t == 0) {
        float tot = wsum[0] + wsum[1] + wsum[2] + wsum[3];
        pooled[plane] = tot * (1.0f / (float)HW);
    }
}

// ---------------------------------------------------------------------------
// Kernel 2: kernel generator.  kern[b,o] = relu(dot(pooled[b,:], Wk[o,:]) + bk[o])
// grid = B_*9 blocks; block handles 256 consecutive o for one b.
// ---------------------------------------------------------------------------
__global__ __launch_bounds__(256) void kgen_kernel(const float* __restrict__ pooled,
                                                   const float* __restrict__ Wk,
                                                   const float* __restrict__ bk,
                                                   float* __restrict__ kern) {
    const int b = blockIdx.x / 9;
    const int g = blockIdx.x % 9;
    __shared__ float p[C_];
    p[threadIdx.x] = pooled[b * C_ + threadIdx.x];
    __syncthreads();

    const int o = g * 256 + threadIdx.x;                // 0..2303
    const float4* wrow = (const float4*)(Wk + (size_t)o * C_);  // contiguous row
    const float4* pv   = (const float4*)p;
    float acc = 0.f;
    #pragma unroll 4
    for (int i = 0; i < C_ / 4; ++i) {
        float4 w = wrow[i];
        float4 q = pv[i];
        acc += w.x * q.x + w.y * q.y + w.z * q.z + w.w * q.w;
    }
    acc += bk[o];
    kern[(size_t)b * OC + o] = fmaxf(acc, 0.f);
}

// ---------------------------------------------------------------------------
// Kernel 3: per-plane depthwise 3x3 conv (cross-correlation, zero pad 1).
// One block per (b,c) plane.  Plane staged in zero-padded 58x58 LDS tile.
// Each thread computes 1x4 output strips -> float4 stores.
// ---------------------------------------------------------------------------
__global__ __launch_bounds__(256) void dconv_kernel(const float* __restrict__ x,
                                                    const float* __restrict__ kern,
                                                    float* __restrict__ out) {
    const int plane = blockIdx.x;                       // b*C + c
    __shared__ float lds[58 * 58];                      // padded tile, 13.1 KB
    const int t = threadIdx.x;

    // zero the whole tile (58*58 = 3364 = 841 float4, 16B-aligned)
    float4* l4 = (float4*)lds;
    for (int i = t; i < (58 * 58) / 4; i += 256)
        l4[i] = make_float4(0.f, 0.f, 0.f, 0.f);
    __syncthreads();

    // stage interior: 784 float4 strips, each within one row (56 % 4 == 0)
    const float4* xp = (const float4*)(x + (size_t)plane * HW);
    for (int s = t; s < 784; s += 256) {
        const int r  = s / 14;                          // row 0..55
        const int c0 = (s % 14) * 4;                    // col 0,4,...,52
        float4 v = xp[s];
        const int base = (r + 1) * 58 + c0 + 1;
        lds[base + 0] = v.x; lds[base + 1] = v.y;
        lds[base + 2] = v.z; lds[base + 3] = v.w;
    }

    // 9 block-uniform weights (compiler emits scalar loads)
    const float* kw = kern + (size_t)plane * KK;
    const float w0 = kw[0], w1 = kw[1], w2 = kw[2],
                w3 = kw[3], w4 = kw[4], w5 = kw[5],
                w6 = kw[6], w7 = kw[7], w8 = kw[8];
    __syncthreads();

    float* op = out + (size_t)plane * HW;
    for (int s = t; s < 784; s += 256) {
        const int r  = s / 14;                          // output row 0..55
        const int c0 = (s % 14) * 4;                    // output col base
        // padded coords: output (r,c) reads padded rows r..r+2, cols c..c+2
        float a0[6], a1[6], a2[6];
        #pragma unroll
        for (int j = 0; j < 6; ++j) {
            a0[j] = lds[(r + 0) * 58 + c0 + j];
            a1[j] = lds[(r + 1) * 58 + c0 + j];
            a2[j] = lds[(r + 2) * 58 + c0 + j];
        }
        float4 res;
        res.x = a0[0]*w0 + a0[1]*w1 + a0[2]*w2
              + a1[0]*w3 + a1[1]*w4 + a1[2]*w5
              + a2[0]*w6 + a2[1]*w7 + a2[2]*w8;
        res.y = a0[1]*w0 + a0[2]*w1 + a0[3]*w2
              + a1[1]*w3 + a1[2]*w4 + a1[3]*w5
              + a2[1]*w6 + a2[2]*w7 + a2[3]*w8;
        res.z = a0[2]*w0 + a0[3]*w1 + a0[4]*w2
              + a1[2]*w3 + a1[3]*w4 + a1[4]*w5
              + a2[2]*w6 + a2[3]*w7 + a2[4]*w8;
        res.w = a0[3]*w0 + a0[4]*w1 + a0[5]*w2
              + a1[3]*w3 + a1[4]*w4 + a1[5]*w5
              + a2[3]*w6 + a2[4]*w7 + a2[5]*w8;
        ((float4*)op)[s] = res;
    }
}

extern "C" void kernel_launch(void* const* d_in, const int* in_sizes, int n_in,
                              void* d_out, int out_size, void* d_ws, size_t ws_size,
                              hipStream_t stream) {
    const float* x  = (const float*)d_in[0];   // [B,C,H,W]
    const float* Wk = (const float*)d_in[1];   // [C*K*K, C]
    const float* bk = (const float*)d_in[2];   // [C*K*K]
    float* out = (float*)d_out;                // [B,C,H,W]

    float* pooled = (float*)d_ws;              // B*C  = 8192 floats
    float* kern   = pooled + NPLANES;          // B*OC = 73728 floats

    pool_kernel<<<NPLANES, 256, 0, stream>>>(x, pooled);
    kgen_kernel<<<B_ * 9, 256, 0, stream>>>(pooled, Wk, bk, kern);
    dconv_kernel<<<NPLANES, 256, 0, stream>>>(x, kern, out);
}

// Round 3
// 212.643 us; speedup vs baseline: 1.0473x; 1.0473x over previous
//
#include <hip/hip_runtime.h>

#define B_  32
#define C_  256
#define H_  56
#define W_  56
#define HW  3136      // H_*W_
#define KK  9
#define OC  2304      // C_*K*K
#define NPLANES (B_*C_)   // 8192

typedef float v4f __attribute__((ext_vector_type(4)));  // native vector for NT stores

// ---------------------------------------------------------------------------
// Kernel 1: global average pool.  One WAVE per (b,c) plane, 4 planes/block.
// No LDS, no __syncthreads — pure shuffle reduction.
// ---------------------------------------------------------------------------
__global__ __launch_bounds__(256) void pool_kernel(const float* __restrict__ x,
                                                   float* __restrict__ pooled) {
    const int wid  = threadIdx.x >> 6;
    const int lane = threadIdx.x & 63;
    const int plane = blockIdx.x * 4 + wid;             // 2048 blocks * 4 waves
    const float4* xp = (const float4*)(x + (size_t)plane * HW);

    float s = 0.f;
    #pragma unroll
    for (int k = 0; k < 12; ++k) {                      // 12*64 = 768 strips
        float4 v = xp[lane + k * 64];
        s += (v.x + v.y) + (v.z + v.w);
    }
    if (lane < 16) {                                    // remainder 768..783
        float4 v = xp[768 + lane];
        s += (v.x + v.y) + (v.z + v.w);
    }
    #pragma unroll
    for (int off = 32; off > 0; off >>= 1)
        s += __shfl_down(s, off, 64);
    if (lane == 0)
        pooled[plane] = s * (1.0f / (float)HW);
}

// ---------------------------------------------------------------------------
// Kernel 2: kernel generator.  kern[b,o] = relu(dot(pooled[b,:], Wk[o,:]) + bk[o])
// grid = B_*9 blocks; block handles 256 consecutive o for one b.
// ---------------------------------------------------------------------------
__global__ __launch_bounds__(256) void kgen_kernel(const float* __restrict__ pooled,
                                                   const float* __restrict__ Wk,
                                                   const float* __restrict__ bk,
                                                   float* __restrict__ kern) {
    const int b = blockIdx.x / 9;
    const int g = blockIdx.x % 9;
    __shared__ float p[C_];
    p[threadIdx.x] = pooled[b * C_ + threadIdx.x];
    __syncthreads();

    const int o = g * 256 + threadIdx.x;                // 0..2303
    const float4* wrow = (const float4*)(Wk + (size_t)o * C_);
    const float4* pv   = (const float4*)p;
    float acc = 0.f;
    #pragma unroll 4
    for (int i = 0; i < C_ / 4; ++i) {
        float4 w = wrow[i];
        float4 q = pv[i];
        acc += w.x * q.x + w.y * q.y + w.z * q.z + w.w * q.w;
    }
    acc += bk[o];
    kern[(size_t)b * OC + o] = fmaxf(acc, 0.f);
}

// ---------------------------------------------------------------------------
// Kernel 3: per-plane depthwise 3x3 conv (cross-correlation, zero pad 1).
// One block per plane.  Loads issued first, halo-only zeroing, single sync,
// float2 LDS reads (8B-aligned: pitch 58 even, c0 multiple of 4),
// nontemporal float4 stores (via native ext_vector type).
// ---------------------------------------------------------------------------
__global__ __launch_bounds__(256) void dconv_kernel(const float* __restrict__ x,
                                                    const float* __restrict__ kern,
                                                    float* __restrict__ out) {
    const int plane = blockIdx.x;
    __shared__ float lds[58 * 58];
    const int t = threadIdx.x;

    // Issue all global loads up front (784 float4 strips over 256 threads).
    const float4* xp = (const float4*)(x + (size_t)plane * HW);
    float4 v0 = xp[t];
    float4 v1 = xp[t + 256];
    float4 v2 = xp[t + 512];
    float4 v3 = make_float4(0.f, 0.f, 0.f, 0.f);
    if (t < 16) v3 = xp[t + 768];

    // Zero only the halo (rows 0,57; cols 0,57).
    if (t < 58) { lds[t] = 0.f; lds[57 * 58 + t] = 0.f; }
    if (t < 56) { lds[(t + 1) * 58] = 0.f; lds[(t + 1) * 58 + 57] = 0.f; }

    // Stage interior (rows 1..56, cols 1..56) — disjoint from halo.
    {
        int s, r, c0, base;
        s = t;        r = s / 14; c0 = (s % 14) * 4; base = (r + 1) * 58 + c0 + 1;
        lds[base] = v0.x; lds[base + 1] = v0.y; lds[base + 2] = v0.z; lds[base + 3] = v0.w;
        s = t + 256;  r = s / 14; c0 = (s % 14) * 4; base = (r + 1) * 58 + c0 + 1;
        lds[base] = v1.x; lds[base + 1] = v1.y; lds[base + 2] = v1.z; lds[base + 3] = v1.w;
        s = t + 512;  r = s / 14; c0 = (s % 14) * 4; base = (r + 1) * 58 + c0 + 1;
        lds[base] = v2.x; lds[base + 1] = v2.y; lds[base + 2] = v2.z; lds[base + 3] = v2.w;
        if (t < 16) {
            s = t + 768; r = s / 14; c0 = (s % 14) * 4; base = (r + 1) * 58 + c0 + 1;
            lds[base] = v3.x; lds[base + 1] = v3.y; lds[base + 2] = v3.z; lds[base + 3] = v3.w;
        }
    }

    // Block-uniform weights -> scalar loads.
    const float* kw = kern + (size_t)plane * KK;
    const float w0 = kw[0], w1 = kw[1], w2 = kw[2],
                w3 = kw[3], w4 = kw[4], w5 = kw[5],
                w6 = kw[6], w7 = kw[7], w8 = kw[8];

    __syncthreads();

    float* op = out + (size_t)plane * HW;

    auto do_strip = [&](int s) {
        const int r  = s / 14;                          // output row 0..55
        const int c0 = (s % 14) * 4;                    // output col base (mult of 4)
        const float* R0 = &lds[(r + 0) * 58 + c0];      // 8B-aligned
        const float* R1 = &lds[(r + 1) * 58 + c0];
        const float* R2 = &lds[(r + 2) * 58 + c0];
        float2 q00 = *(const float2*)(R0),     q01 = *(const float2*)(R0 + 2), q02 = *(const float2*)(R0 + 4);
        float2 q10 = *(const float2*)(R1),     q11 = *(const float2*)(R1 + 2), q12 = *(const float2*)(R1 + 4);
        float2 q20 = *(const float2*)(R2),     q21 = *(const float2*)(R2 + 2), q22 = *(const float2*)(R2 + 4);
        const float a0 = q00.x, a1 = q00.y, a2 = q01.x, a3 = q01.y, a4 = q02.x, a5 = q02.y;
        const float b0 = q10.x, b1 = q10.y, b2 = q11.x, b3 = q11.y, b4 = q12.x, b5 = q12.y;
        const float c0f = q20.x, c1 = q20.y, c2 = q21.x, c3 = q21.y, c4 = q22.x, c5 = q22.y;
        v4f res;
        res.x = a0*w0 + a1*w1 + a2*w2 + b0*w3 + b1*w4 + b2*w5 + c0f*w6 + c1*w7 + c2*w8;
        res.y = a1*w0 + a2*w1 + a3*w2 + b1*w3 + b2*w4 + b3*w5 + c1*w6 + c2*w7 + c3*w8;
        res.z = a2*w0 + a3*w1 + a4*w2 + b2*w3 + b3*w4 + b4*w5 + c2*w6 + c3*w7 + c4*w8;
        res.w = a3*w0 + a4*w1 + a5*w2 + b3*w3 + b4*w4 + b5*w5 + c3*w6 + c4*w7 + c5*w8;
        __builtin_nontemporal_store(res, (v4f*)op + s);
    };

    do_strip(t);
    do_strip(t + 256);
    do_strip(t + 512);
    if (t < 16) do_strip(t + 768);
}

extern "C" void kernel_launch(void* const* d_in, const int* in_sizes, int n_in,
                              void* d_out, int out_size, void* d_ws, size_t ws_size,
                              hipStream_t stream) {
    const float* x  = (const float*)d_in[0];   // [B,C,H,W]
    const float* Wk = (const float*)d_in[1];   // [C*K*K, C]
    const float* bk = (const float*)d_in[2];   // [C*K*K]
    float* out = (float*)d_out;                // [B,C,H,W]

    float* pooled = (float*)d_ws;              // B*C  = 8192 floats
    float* kern   = pooled + NPLANES;          // B*OC = 73728 floats

    pool_kernel<<<NPLANES / 4, 256, 0, stream>>>(x, pooled);
    kgen_kernel<<<B_ * 9, 256, 0, stream>>>(pooled, Wk, bk, kern);
    dconv_kernel<<<NPLANES, 256, 0, stream>>>(x, kern, out);
}

// Round 4
// 199.396 us; speedup vs baseline: 1.1168x; 1.0664x over previous
//
#include <hip/hip_runtime.h>

#define B_  32
#define C_  256
#define H_  56
#define W_  56
#define HW  3136      // H_*W_
#define KK  9
#define OC  2304      // C_*K*K
#define NPLANES (B_*C_)   // 8192

typedef float v4f __attribute__((ext_vector_type(4)));  // native vector for NT stores

// ---------------------------------------------------------------------------
// Kernel 1: global average pool.  One WAVE per (b,c) plane, 4 planes/block.
// No LDS, no __syncthreads — pure shuffle reduction.  Regular (non-NT) loads
// keep x resident in L2/L3 for the conv pass.
// ---------------------------------------------------------------------------
__global__ __launch_bounds__(256) void pool_kernel(const float* __restrict__ x,
                                                   float* __restrict__ pooled) {
    const int wid  = threadIdx.x >> 6;
    const int lane = threadIdx.x & 63;
    const int plane = blockIdx.x * 4 + wid;             // 2048 blocks * 4 waves
    const float4* xp = (const float4*)(x + (size_t)plane * HW);

    float s = 0.f;
    #pragma unroll
    for (int k = 0; k < 12; ++k) {                      // 12*64 = 768 strips
        float4 v = xp[lane + k * 64];
        s += (v.x + v.y) + (v.z + v.w);
    }
    if (lane < 16) {                                    // remainder 768..783
        float4 v = xp[768 + lane];
        s += (v.x + v.y) + (v.z + v.w);
    }
    #pragma unroll
    for (int off = 32; off > 0; off >>= 1)
        s += __shfl_down(s, off, 64);
    if (lane == 0)
        pooled[plane] = s * (1.0f / (float)HW);
}

// ---------------------------------------------------------------------------
// Kernel 2 (fused): per-plane kernel-generation + depthwise 3x3 conv.
// One block per (b,c) plane.
//   * threads 0..143 compute the 9 filter taps: 16 lanes per tap, each lane
//     a 16-channel partial dot of pooled[b,:] with Wk row, shuffle-reduced.
//     Overlaps the in-flight x global loads.
//   * plane staged in zero-padded 58x58 LDS tile (halo-only zeroing).
//   * 2x4 output tiles per thread: 12 ds_read_b64 per 8 outputs (was 18),
//     cutting LDS read bytes/instructions by 33% -> purely write-bound.
// ---------------------------------------------------------------------------
__global__ __launch_bounds__(256) void dconv_kernel(const float* __restrict__ x,
                                                    const float* __restrict__ pooled,
                                                    const float* __restrict__ Wk,
                                                    const float* __restrict__ bk,
                                                    float* __restrict__ out) {
    const int plane = blockIdx.x;                       // b*C_ + c
    const int b = plane >> 8;
    const int c = plane & 255;
    __shared__ float lds[58 * 58];
    __shared__ float wsh[KK];
    const int t = threadIdx.x;

    // Issue all x global loads up front (784 float4 strips over 256 threads).
    const float4* xp = (const float4*)(x + (size_t)plane * HW);
    float4 v0 = xp[t];
    float4 v1 = xp[t + 256];
    float4 v2 = xp[t + 512];
    float4 v3 = make_float4(0.f, 0.f, 0.f, 0.f);
    if (t < 16) v3 = xp[t + 768];

    // Kernel generation: tap o = t/16, lane chunk = (t%16)*16 channels.
    if (t < 144) {
        const int o  = t >> 4;                          // 0..8
        const int ch = (t & 15) << 4;                   // 0,16,...,240
        const int og = c * KK + o;                      // global output row
        const float4* wr = (const float4*)(Wk + (size_t)og * C_ + ch);
        const float4* pr = (const float4*)(pooled + b * C_ + ch);
        float s = 0.f;
        #pragma unroll
        for (int i = 0; i < 4; ++i) {
            float4 w = wr[i];
            float4 p = pr[i];
            s += w.x * p.x + w.y * p.y + w.z * p.z + w.w * p.w;
        }
        #pragma unroll
        for (int off = 8; off > 0; off >>= 1)           // reduce 16-lane groups
            s += __shfl_down(s, off, 16);
        if ((t & 15) == 0)
            wsh[o] = fmaxf(s + bk[og], 0.f);
    }

    // Zero only the halo (rows 0,57; cols 0,57).
    if (t < 58) { lds[t] = 0.f; lds[57 * 58 + t] = 0.f; }
    if (t < 56) { lds[(t + 1) * 58] = 0.f; lds[(t + 1) * 58 + 57] = 0.f; }

    // Stage interior (rows 1..56, cols 1..56) — disjoint from halo.
    {
        int s, r, c0, base;
        s = t;        r = s / 14; c0 = (s % 14) * 4; base = (r + 1) * 58 + c0 + 1;
        lds[base] = v0.x; lds[base + 1] = v0.y; lds[base + 2] = v0.z; lds[base + 3] = v0.w;
        s = t + 256;  r = s / 14; c0 = (s % 14) * 4; base = (r + 1) * 58 + c0 + 1;
        lds[base] = v1.x; lds[base + 1] = v1.y; lds[base + 2] = v1.z; lds[base + 3] = v1.w;
        s = t + 512;  r = s / 14; c0 = (s % 14) * 4; base = (r + 1) * 58 + c0 + 1;
        lds[base] = v2.x; lds[base + 1] = v2.y; lds[base + 2] = v2.z; lds[base + 3] = v2.w;
        if (t < 16) {
            s = t + 768; r = s / 14; c0 = (s % 14) * 4; base = (r + 1) * 58 + c0 + 1;
            lds[base] = v3.x; lds[base + 1] = v3.y; lds[base + 2] = v3.z; lds[base + 3] = v3.w;
        }
    }

    __syncthreads();

    const float w0 = wsh[0], w1 = wsh[1], w2 = wsh[2],
                w3 = wsh[3], w4 = wsh[4], w5 = wsh[5],
                w6 = wsh[6], w7 = wsh[7], w8 = wsh[8];

    float* op = out + (size_t)plane * HW;

    // 2x4 output tiles: i in [0,392); rp = row pair, cq*4 = col base.
    for (int i = t; i < 392; i += 256) {
        const int rp = i / 14;                          // 0..27 -> out rows 2rp, 2rp+1
        const int c0 = (i % 14) * 4;                    // 0,4,...,52
        const float* R0 = &lds[(2 * rp + 0) * 58 + c0]; // 8B-aligned (pitch even, c0 even)
        const float* R1 = &lds[(2 * rp + 1) * 58 + c0];
        const float* R2 = &lds[(2 * rp + 2) * 58 + c0];
        const float* R3 = &lds[(2 * rp + 3) * 58 + c0];
        float2 p0 = *(const float2*)(R0), p1 = *(const float2*)(R0 + 2), p2 = *(const float2*)(R0 + 4);
        float2 q0 = *(const float2*)(R1), q1 = *(const float2*)(R1 + 2), q2 = *(const float2*)(R1 + 4);
        float2 r0 = *(const float2*)(R2), r1 = *(const float2*)(R2 + 2), r2 = *(const float2*)(R2 + 4);
        float2 s0 = *(const float2*)(R3), s1 = *(const float2*)(R3 + 2), s2 = *(const float2*)(R3 + 4);
        const float a0 = p0.x, a1 = p0.y, a2 = p1.x, a3 = p1.y, a4 = p2.x, a5 = p2.y;
        const float b0 = q0.x, b1 = q0.y, b2 = q1.x, b3 = q1.y, b4 = q2.x, b5 = q2.y;
        const float c0f = r0.x, c1f = r0.y, c2f = r1.x, c3f = r1.y, c4f = r2.x, c5f = r2.y;
        const float d0 = s0.x, d1 = s0.y, d2 = s1.x, d3 = s1.y, d4 = s2.x, d5 = s2.y;

        v4f t0, t1;
        t0.x = a0*w0 + a1*w1 + a2*w2 + b0*w3 + b1*w4 + b2*w5 + c0f*w6 + c1f*w7 + c2f*w8;
        t0.y = a1*w0 + a2*w1 + a3*w2 + b1*w3 + b2*w4 + b3*w5 + c1f*w6 + c2f*w7 + c3f*w8;
        t0.z = a2*w0 + a3*w1 + a4*w2 + b2*w3 + b3*w4 + b4*w5 + c2f*w6 + c3f*w7 + c4f*w8;
        t0.w = a3*w0 + a4*w1 + a5*w2 + b3*w3 + b4*w4 + b5*w5 + c3f*w6 + c4f*w7 + c5f*w8;
        t1.x = b0*w0 + b1*w1 + b2*w2 + c0f*w3 + c1f*w4 + c2f*w5 + d0*w6 + d1*w7 + d2*w8;
        t1.y = b1*w0 + b2*w1 + b3*w2 + c1f*w3 + c2f*w4 + c3f*w5 + d1*w6 + d2*w7 + d3*w8;
        t1.z = b2*w0 + b3*w1 + b4*w2 + c2f*w3 + c3f*w4 + c4f*w5 + d2*w6 + d3*w7 + d4*w8;
        t1.w = b3*w0 + b4*w1 + b5*w2 + c3f*w3 + c4f*w4 + c5f*w5 + d3*w6 + d4*w7 + d5*w8;

        __builtin_nontemporal_store(t0, (v4f*)(op + (2 * rp + 0) * W_ + c0));
        __builtin_nontemporal_store(t1, (v4f*)(op + (2 * rp + 1) * W_ + c0));
    }
}

extern "C" void kernel_launch(void* const* d_in, const int* in_sizes, int n_in,
                              void* d_out, int out_size, void* d_ws, size_t ws_size,
                              hipStream_t stream) {
    const float* x  = (const float*)d_in[0];   // [B,C,H,W]
    const float* Wk = (const float*)d_in[1];   // [C*K*K, C]
    const float* bk = (const float*)d_in[2];   // [C*K*K]
    float* out = (float*)d_out;                // [B,C,H,W]

    float* pooled = (float*)d_ws;              // B*C = 8192 floats

    pool_kernel<<<NPLANES / 4, 256, 0, stream>>>(x, pooled);
    dconv_kernel<<<NPLANES, 256, 0, stream>>>(x, pooled, Wk, bk, out);
}